// Round 1
// baseline (731.740 us; speedup 1.0000x reference)
//
#include <hip/hip_runtime.h>
#include <math.h>

// N=1M nodes, E=32M edges. Counting-sort edges by dst-bucket, then both
// aggregation passes use LDS atomics only (R3 showed global atomics cap at
// ~20.7 G/s). R5: permute restructured for occupancy. R6 (this round):
// agg kernels were latency-bound (VALUBusy 2.3%, Occupancy 44%, grid=245
// blocks): split each bucket across SPLITS=4 blocks (grid 980, ~full wave
// occupancy), 2-deep vuint4 pipeline (8 gathers in flight/thread),
// nontemporal record-stream loads (keep m/cls2 L2-resident), 2-bit packed
// class array (256 KB, L2-resident). Partial LDS accumulators merge via
// contiguous global atomics; classify is a small packed kernel.
//
// record = (src << 12) | (dst & 4095)   [src < 2^20]
// ws: m (4MB) | gcur (1KB) | y/pk alias (4MB) | cls2 (256KB) | gsorted (NB*CAP*4)

#define EPS 1e-15f
#define CHUNK 8192
#define PTHREADS 512
#define NBINS 256
#define BNODES 4096
#define SPLITS 4

typedef int          vint4  __attribute__((ext_vector_type(4)));
typedef unsigned int vuint4 __attribute__((ext_vector_type(4)));

// ===================== sort path =====================

__global__ __launch_bounds__(256)
void k_prep2(const float2* __restrict__ x, const float* __restrict__ W,
             float* __restrict__ m, float* __restrict__ y,
             unsigned int* __restrict__ gcur,
             int N, int NB, unsigned int CAP) {
    int i = blockIdx.x * 256 + threadIdx.x;
    if (i < N) {
        float2 v = x[i];
        float inv = 1.0f / (sqrtf(v.x * v.x + v.y * v.y) + EPS);
        m[i] = (v.x * inv) * W[0] + (v.y * inv) * W[2];
        y[i] = 0.0f;
    }
    if (i < NB) gcur[i] = (unsigned)i * CAP;
}

__global__ __launch_bounds__(PTHREADS)
void k_permute(const int* __restrict__ src, const int* __restrict__ dst,
               unsigned int* __restrict__ gsorted, unsigned int* __restrict__ gcur,
               int E) {
    __shared__ unsigned int  sh_sorted[CHUNK];   // 32 KB staged records
    __shared__ unsigned char sh_bin[CHUNK];      //  8 KB bin of each slot
    __shared__ unsigned int  sh_hist[NBINS];     //  1 KB counts -> cursor
    __shared__ unsigned int  sh_loff[NBINS];     //  1 KB local bin starts
    __shared__ unsigned int  sh_delta[NBINS];    //  1 KB global base - local start
    __shared__ unsigned int  sh_scan[NBINS];     //  1 KB scan scratch
    const int tid = threadIdx.x;
    const long long e0 = (long long)blockIdx.x * CHUNK;
    const int n = (int)min((long long)CHUNK, (long long)E - e0);
    const int nv4 = (n >> 2) << 2;

    if (tid < NBINS) sh_hist[tid] = 0u;
    __syncthreads();

    // phase 1: bucket histogram of dst (cached loads; re-read in phase 3 hits L2)
    #pragma unroll
    for (int k = 0; k < CHUNK / (PTHREADS * 4); ++k) {
        int o = (k * PTHREADS + tid) * 4;
        if (o < nv4) {
            vint4 d = *(const vint4*)(dst + e0 + o);
            atomicAdd(&sh_hist[((unsigned)d.x) >> 12], 1u);
            atomicAdd(&sh_hist[((unsigned)d.y) >> 12], 1u);
            atomicAdd(&sh_hist[((unsigned)d.z) >> 12], 1u);
            atomicAdd(&sh_hist[((unsigned)d.w) >> 12], 1u);
        }
    }
    for (int j = nv4 + tid; j < n; j += PTHREADS)
        atomicAdd(&sh_hist[((unsigned)dst[e0 + j]) >> 12], 1u);
    __syncthreads();

    // phase 2: scan 256 bins + global range reservation (1 atomic per nonempty bin)
    if (tid < NBINS) sh_scan[tid] = sh_hist[tid];
    __syncthreads();
    for (int off = 1; off < NBINS; off <<= 1) {
        unsigned v = 0;
        if (tid < NBINS && tid >= off) v = sh_scan[tid - off];
        __syncthreads();
        if (tid < NBINS) sh_scan[tid] += v;
        __syncthreads();
    }
    if (tid < NBINS) {
        unsigned h = sh_hist[tid];
        unsigned lo = sh_scan[tid] - h;     // exclusive prefix
        sh_loff[tid] = lo;
        if (h) sh_delta[tid] = atomicAdd(&gcur[tid], h) - lo;
    }
    __syncthreads();
    if (tid < NBINS) sh_hist[tid] = sh_loff[tid];   // running cursor
    __syncthreads();

    // phase 3: re-read src+dst, scatter packed records into LDS in bin order
    #pragma unroll
    for (int k = 0; k < CHUNK / (PTHREADS * 4); ++k) {
        int o = (k * PTHREADS + tid) * 4;
        if (o < nv4) {
            vint4 s = __builtin_nontemporal_load((const vint4*)(src + e0 + o));
            vint4 d = *(const vint4*)(dst + e0 + o);
            unsigned b, p;
            b = ((unsigned)d.x) >> 12; p = atomicAdd(&sh_hist[b], 1u);
            sh_sorted[p] = ((unsigned)s.x << 12) | ((unsigned)d.x & 4095u); sh_bin[p] = (unsigned char)b;
            b = ((unsigned)d.y) >> 12; p = atomicAdd(&sh_hist[b], 1u);
            sh_sorted[p] = ((unsigned)s.y << 12) | ((unsigned)d.y & 4095u); sh_bin[p] = (unsigned char)b;
            b = ((unsigned)d.z) >> 12; p = atomicAdd(&sh_hist[b], 1u);
            sh_sorted[p] = ((unsigned)s.z << 12) | ((unsigned)d.z & 4095u); sh_bin[p] = (unsigned char)b;
            b = ((unsigned)d.w) >> 12; p = atomicAdd(&sh_hist[b], 1u);
            sh_sorted[p] = ((unsigned)s.w << 12) | ((unsigned)d.w & 4095u); sh_bin[p] = (unsigned char)b;
        }
    }
    for (int j = nv4 + tid; j < n; j += PTHREADS) {
        unsigned dv = (unsigned)dst[e0 + j], sv = (unsigned)src[e0 + j];
        unsigned b = dv >> 12;
        unsigned p = atomicAdd(&sh_hist[b], 1u);
        sh_sorted[p] = (sv << 12) | (dv & 4095u);
        sh_bin[p] = (unsigned char)b;
    }
    __syncthreads();

    // phase 4: coalesced copy-out via direct bin lookup
    for (int t = tid; t < n; t += PTHREADS)
        gsorted[sh_delta[sh_bin[t]] + (unsigned)t] = sh_sorted[t];
}

// pass 1 aggregate: y += partial sum m[src] per dst. Bucket b handled by
// SPLITS blocks (split-strided vec4 slices), each with a private LDS
// accumulator merged via contiguous global f32 atomics.
__global__ __launch_bounds__(1024)
void k_agg1s(const unsigned int* __restrict__ gsorted, const unsigned int* __restrict__ gcur,
             const float* __restrict__ m, float* __restrict__ y,
             int N, unsigned int CAP, int NB) {
    __shared__ float yloc[BNODES];   // 16 KB
    const int tid = threadIdx.x;
    const int b = blockIdx.x % NB;
    const int split = blockIdx.x / NB;
    for (int j = tid; j < BNODES; j += 1024) yloc[j] = 0.0f;
    __syncthreads();
    const unsigned base = (unsigned)b * CAP;
    const unsigned cnt = gcur[b] - base;
    const unsigned nv = cnt >> 2;
    const vuint4* pv = (const vuint4*)(gsorted + base);
    const unsigned stride = SPLITS * 1024u;
    unsigned k = (unsigned)split * 1024u + (unsigned)tid;
    // 2-deep: 2 record loads + 8 independent gathers in flight per thread
    for (; k + stride < nv; k += 2u * stride) {
        vuint4 p0 = __builtin_nontemporal_load(pv + k);
        vuint4 p1 = __builtin_nontemporal_load(pv + k + stride);
        float m0 = m[p0.x >> 12], m1 = m[p0.y >> 12];
        float m2 = m[p0.z >> 12], m3 = m[p0.w >> 12];
        float m4 = m[p1.x >> 12], m5 = m[p1.y >> 12];
        float m6 = m[p1.z >> 12], m7 = m[p1.w >> 12];
        atomicAdd(&yloc[p0.x & 4095u], m0);
        atomicAdd(&yloc[p0.y & 4095u], m1);
        atomicAdd(&yloc[p0.z & 4095u], m2);
        atomicAdd(&yloc[p0.w & 4095u], m3);
        atomicAdd(&yloc[p1.x & 4095u], m4);
        atomicAdd(&yloc[p1.y & 4095u], m5);
        atomicAdd(&yloc[p1.z & 4095u], m6);
        atomicAdd(&yloc[p1.w & 4095u], m7);
    }
    for (; k < nv; k += stride) {
        vuint4 p = __builtin_nontemporal_load(pv + k);
        float m0 = m[p.x >> 12], m1 = m[p.y >> 12];
        float m2 = m[p.z >> 12], m3 = m[p.w >> 12];
        atomicAdd(&yloc[p.x & 4095u], m0);
        atomicAdd(&yloc[p.y & 4095u], m1);
        atomicAdd(&yloc[p.z & 4095u], m2);
        atomicAdd(&yloc[p.w & 4095u], m3);
    }
    if (split == 0) {
        for (unsigned i = (nv << 2) + tid; i < cnt; i += 1024) {
            unsigned p = gsorted[base + i];
            atomicAdd(&yloc[p & 4095u], m[p >> 12]);
        }
    }
    __syncthreads();
    const int nbase = b * BNODES;
    for (int j = tid; j < BNODES; j += 1024) {
        float v = yloc[j];
        int node = nbase + j;
        if (node < N && v != 0.0f) unsafeAtomicAdd(&y[node], v);
    }
}

// classify: pack 16 node classes per u32 word (2 bits each), zero pk.
// pk aliases y (read y first, then overwrite with 0) — each thread owns
// its 16 slots exclusively, so the alias is safe.
__global__ __launch_bounds__(256)
void k_classify2(const float* __restrict__ y, unsigned int* __restrict__ cls2,
                 unsigned int* __restrict__ pk, int N) {
    int i = blockIdx.x * 256 + threadIdx.x;   // word index
    int nw = (N + 15) >> 4;
    if (i >= nw) return;
    int n0 = i << 4;
    unsigned w = 0u;
    if (n0 + 16 <= N) {
        const float4* yv = (const float4*)(y + n0);
        float4 v0 = yv[0], v1 = yv[1], v2 = yv[2], v3 = yv[3];
        float vv[16] = {v0.x, v0.y, v0.z, v0.w, v1.x, v1.y, v1.z, v1.w,
                        v2.x, v2.y, v2.z, v2.w, v3.x, v3.y, v3.z, v3.w};
        #pragma unroll
        for (int j = 0; j < 16; ++j) {
            unsigned c = (vv[j] > 0.0f) ? 1u : ((vv[j] < 0.0f) ? 2u : 0u);
            w |= c << (j * 2);
        }
        int4 z = {0, 0, 0, 0};
        int4* pz = (int4*)(pk + n0);
        pz[0] = z; pz[1] = z; pz[2] = z; pz[3] = z;
    } else {
        for (int j = 0; n0 + j < N; ++j) {
            float v = y[n0 + j];
            unsigned c = (v > 0.0f) ? 1u : ((v < 0.0f) ? 2u : 0u);
            w |= c << (j * 2);
            pk[n0 + j] = 0u;
        }
    }
    cls2[i] = w;
}

// pass 2 aggregate: packed class counts per dst, split like pass 1.
// class word gather hits a 256 KB L2-resident array.
__global__ __launch_bounds__(1024)
void k_agg2s(const unsigned int* __restrict__ gsorted, const unsigned int* __restrict__ gcur,
             const unsigned int* __restrict__ cls2, unsigned int* __restrict__ pk,
             int N, unsigned int CAP, int NB) {
    __shared__ unsigned int pkloc[BNODES];   // 16 KB
    const int tid = threadIdx.x;
    const int b = blockIdx.x % NB;
    const int split = blockIdx.x / NB;
    for (int j = tid; j < BNODES; j += 1024) pkloc[j] = 0u;
    __syncthreads();
    const unsigned base = (unsigned)b * CAP;
    const unsigned cnt = gcur[b] - base;
    const unsigned nv = cnt >> 2;
    const vuint4* pv = (const vuint4*)(gsorted + base);
    auto dec = [&](unsigned s) -> unsigned int {
        unsigned wd = cls2[s >> 4];
        unsigned cl = (wd >> ((s & 15u) << 1)) & 3u;
        // cl: 0 -> 0, 1 -> 1<<16, 2 -> 1
        return ((cl & 1u) << 16) | (cl >> 1);
    };
    const unsigned stride = SPLITS * 1024u;
    unsigned k = (unsigned)split * 1024u + (unsigned)tid;
    for (; k + stride < nv; k += 2u * stride) {
        vuint4 p0 = __builtin_nontemporal_load(pv + k);
        vuint4 p1 = __builtin_nontemporal_load(pv + k + stride);
        unsigned d0 = dec(p0.x >> 12), d1 = dec(p0.y >> 12);
        unsigned d2 = dec(p0.z >> 12), d3 = dec(p0.w >> 12);
        unsigned d4 = dec(p1.x >> 12), d5 = dec(p1.y >> 12);
        unsigned d6 = dec(p1.z >> 12), d7 = dec(p1.w >> 12);
        atomicAdd(&pkloc[p0.x & 4095u], d0);
        atomicAdd(&pkloc[p0.y & 4095u], d1);
        atomicAdd(&pkloc[p0.z & 4095u], d2);
        atomicAdd(&pkloc[p0.w & 4095u], d3);
        atomicAdd(&pkloc[p1.x & 4095u], d4);
        atomicAdd(&pkloc[p1.y & 4095u], d5);
        atomicAdd(&pkloc[p1.z & 4095u], d6);
        atomicAdd(&pkloc[p1.w & 4095u], d7);
    }
    for (; k < nv; k += stride) {
        vuint4 p = __builtin_nontemporal_load(pv + k);
        unsigned d0 = dec(p.x >> 12), d1 = dec(p.y >> 12);
        unsigned d2 = dec(p.z >> 12), d3 = dec(p.w >> 12);
        atomicAdd(&pkloc[p.x & 4095u], d0);
        atomicAdd(&pkloc[p.y & 4095u], d1);
        atomicAdd(&pkloc[p.z & 4095u], d2);
        atomicAdd(&pkloc[p.w & 4095u], d3);
    }
    if (split == 0) {
        for (unsigned i = (nv << 2) + tid; i < cnt; i += 1024) {
            unsigned p = gsorted[base + i];
            atomicAdd(&pkloc[p & 4095u], dec(p >> 12));
        }
    }
    __syncthreads();
    const int nbase = b * BNODES;
    for (int j = tid; j < BNODES; j += 1024) {
        unsigned v = pkloc[j];
        int node = nbase + j;
        if (node < N && v) atomicAdd(&pk[node], v);
    }
}

// ===================== fallback path (R3, atomic-based) =====================

__global__ __launch_bounds__(256)
void k_prep(const float2* __restrict__ x, const float* __restrict__ W,
            float* __restrict__ m, float* __restrict__ y,
            unsigned int* __restrict__ pk, int N) {
    int i = blockIdx.x * blockDim.x + threadIdx.x;
    if (i < N) {
        float2 v = x[i];
        float inv = 1.0f / (sqrtf(v.x * v.x + v.y * v.y) + EPS);
        m[i]  = (v.x * inv) * W[0] + (v.y * inv) * W[2];
        y[i]  = 0.0f;
        pk[i] = 0u;
    }
}

__global__ __launch_bounds__(256)
void k_scatter1(const int* __restrict__ src, const int* __restrict__ dst,
                const float* __restrict__ m, float* __restrict__ y, int E) {
    int t = blockIdx.x * blockDim.x + threadIdx.x;
    int i = t * 8;
    if (i + 8 <= E) {
        vint4 s0 = __builtin_nontemporal_load((const vint4*)(src + i));
        vint4 s1 = __builtin_nontemporal_load((const vint4*)(src + i + 4));
        vint4 d0 = __builtin_nontemporal_load((const vint4*)(dst + i));
        vint4 d1 = __builtin_nontemporal_load((const vint4*)(dst + i + 4));
        unsafeAtomicAdd(&y[d0.x], m[s0.x]);
        unsafeAtomicAdd(&y[d0.y], m[s0.y]);
        unsafeAtomicAdd(&y[d0.z], m[s0.z]);
        unsafeAtomicAdd(&y[d0.w], m[s0.w]);
        unsafeAtomicAdd(&y[d1.x], m[s1.x]);
        unsafeAtomicAdd(&y[d1.y], m[s1.y]);
        unsafeAtomicAdd(&y[d1.z], m[s1.z]);
        unsafeAtomicAdd(&y[d1.w], m[s1.w]);
    } else if (i < E) {
        for (int j = i; j < E; ++j)
            unsafeAtomicAdd(&y[dst[j]], m[src[j]]);
    }
}

__global__ __launch_bounds__(256)
void k_classify(const float* __restrict__ y, unsigned char* __restrict__ cls, int N) {
    int i = blockIdx.x * blockDim.x + threadIdx.x;
    if (i < N) {
        float v = y[i];
        cls[i] = (v > 0.0f) ? 1 : ((v < 0.0f) ? 2 : 0);
    }
}

__global__ __launch_bounds__(256)
void k_scatter2(const int* __restrict__ src, const int* __restrict__ dst,
                const unsigned char* __restrict__ cls, unsigned int* __restrict__ pk,
                int E) {
    int t = blockIdx.x * blockDim.x + threadIdx.x;
    int i = t * 8;
    auto dec = [](unsigned char c) -> unsigned int {
        return (c == 1) ? 65536u : ((c == 2) ? 1u : 0u);
    };
    if (i + 8 <= E) {
        vint4 s0 = __builtin_nontemporal_load((const vint4*)(src + i));
        vint4 s1 = __builtin_nontemporal_load((const vint4*)(src + i + 4));
        vint4 d0 = __builtin_nontemporal_load((const vint4*)(dst + i));
        vint4 d1 = __builtin_nontemporal_load((const vint4*)(dst + i + 4));
        atomicAdd(&pk[d0.x], dec(cls[s0.x]));
        atomicAdd(&pk[d0.y], dec(cls[s0.y]));
        atomicAdd(&pk[d0.z], dec(cls[s0.z]));
        atomicAdd(&pk[d0.w], dec(cls[s0.w]));
        atomicAdd(&pk[d1.x], dec(cls[s1.x]));
        atomicAdd(&pk[d1.y], dec(cls[s1.y]));
        atomicAdd(&pk[d1.z], dec(cls[s1.z]));
        atomicAdd(&pk[d1.w], dec(cls[s1.w]));
    } else if (i < E) {
        for (int j = i; j < E; ++j)
            atomicAdd(&pk[dst[j]], dec(cls[src[j]]));
    }
}

__global__ __launch_bounds__(256)
void k_final(const unsigned int* __restrict__ pk, const float* __restrict__ W,
             const float* __restrict__ fw, float* __restrict__ out, int N) {
    int i = blockIdx.x * blockDim.x + threadIdx.x;
    if (i < N) {
        unsigned p = pk[i];
        float c0 = (float)(p >> 16);
        float c1 = (float)(p & 0xFFFFu);
        float x0 = fmaxf(c0 * W[0] + c1 * W[2], 0.0f);
        float x1 = fmaxf(c0 * W[1] + c1 * W[3], 0.0f);
        float z = x0 * fw[0] + x1 * fw[1];
        out[i] = 1.0f / (1.0f + expf(-z));
    }
}

// ===================== launch =====================

extern "C" void kernel_launch(void* const* d_in, const int* in_sizes, int n_in,
                              void* d_out, int out_size, void* d_ws, size_t ws_size,
                              hipStream_t stream) {
    const float* x  = (const float*)d_in[0];
    const int*   ei = (const int*)d_in[1];
    const float* W  = (const float*)d_in[2];
    const float* fw = (const float*)d_in[3];
    float*       out = (float*)d_out;

    const int N = in_sizes[0] / 2;
    const int E = in_sizes[1] / 2;
    const int* src = ei;
    const int* dst = ei + E;

    const int B  = 256;
    const int gN = (N + B - 1) / B;

    // sort-path sizing: 256 bins of 4096 nodes
    const int NB = (N + BNODES - 1) / BNODES;
    double mean = (double)E / ((double)N / (double)BNODES);
    unsigned CAP = (unsigned)(mean + 8.0 * sqrt(mean) + 1024.0);
    CAP = (CAP + 1023u) & ~1023u;

    const int NW = (N + 15) >> 4;   // packed class words

    char* p = (char*)d_ws;
    float*         m_s   = (float*)p;          p += (((size_t)N * 4 + 255) & ~255ULL);
    unsigned int*  gcur  = (unsigned int*)p;   p += (((size_t)NB * 4 + 255) & ~255ULL);
    float*         y_s   = (float*)p;          p += (((size_t)N * 4 + 255) & ~255ULL);
    unsigned int*  cls2  = (unsigned int*)p;   p += (((size_t)NW * 4 + 255) & ~255ULL);
    unsigned int*  gsorted = (unsigned int*)p;
    size_t need = (size_t)(p - (char*)d_ws) + (size_t)NB * CAP * 4ULL;

    if (ws_size >= need && N <= (1 << 20) && NB <= NBINS) {
        const int gP = (E + CHUNK - 1) / CHUNK;
        unsigned int* pk_s = (unsigned int*)y_s;   // pk aliases y (see k_classify2)
        k_prep2<<<gN, B, 0, stream>>>((const float2*)x, W, m_s, y_s, gcur, N, NB, CAP);
        k_permute<<<gP, PTHREADS, 0, stream>>>(src, dst, gsorted, gcur, E);
        k_agg1s<<<NB * SPLITS, 1024, 0, stream>>>(gsorted, gcur, m_s, y_s, N, CAP, NB);
        k_classify2<<<(NW + B - 1) / B, B, 0, stream>>>(y_s, cls2, pk_s, N);
        k_agg2s<<<NB * SPLITS, 1024, 0, stream>>>(gsorted, gcur, cls2, pk_s, N, CAP, NB);
        k_final<<<gN, B, 0, stream>>>(pk_s, W, fw, out, N);
    } else {
        // fallback: R3 atomic path
        char* q = (char*)d_ws;
        unsigned char* cls = (unsigned char*)q;  q += (((size_t)N + 255) & ~255ULL);
        float*         m   = (float*)q;          q += (((size_t)N * 4 + 255) & ~255ULL);
        float*         y   = (float*)q;          q += (((size_t)N * 4 + 255) & ~255ULL);
        unsigned int*  pk  = (unsigned int*)q;
        const int gE = (E / 8 + B - 1) / B + 1;
        k_prep<<<gN, B, 0, stream>>>((const float2*)x, W, m, y, pk, N);
        k_scatter1<<<gE, B, 0, stream>>>(src, dst, m, y, E);
        k_classify<<<gN, B, 0, stream>>>(y, cls, N);
        k_scatter2<<<gE, B, 0, stream>>>(src, dst, cls, pk, E);
        k_final<<<gN, B, 0, stream>>>(pk, W, fw, out, N);
    }
}